// Round 9
// baseline (128.098 us; speedup 1.0000x reference)
//
#include <hip/hip_runtime.h>
#include <hip/hip_bf16.h>
#include <stdint.h>

// GraphAttentionLayer: B=8, S=2048, F=128, H=4, D=32
// proj: Wh[b,h,s,d] (row-major) AND WhT[b,h,d,s] (transposed) via bf16 MFMA
// attn: barrier-free, LDS-free. One wave = (b, 16 q-rows, t-chunk) x ALL 4
//   heads. adj mask lane-partitioned in registers (read once globally),
//   permuted-K QK^T so softmax registers ARE the PV B-fragments.
//   Fixed-max softmax (max=0), swapped QK^T and swapped PV.

namespace {
constexpr int S = 2048;
constexpr int F = 128;
constexpr int H = 4;
constexpr int D = 32;

typedef __attribute__((ext_vector_type(4))) float f32x4;
typedef __attribute__((ext_vector_type(8))) short s16x8;
typedef __attribute__((ext_vector_type(4))) short s16x4;

__device__ __forceinline__ short f2bf(float f) {
  __hip_bfloat16 h = __float2bfloat16(f);
  short s; __builtin_memcpy(&s, &h, sizeof(s)); return s;
}
__device__ __forceinline__ float bf2f(short s) {
  __hip_bfloat16 h; __builtin_memcpy(&h, &s, sizeof(s));
  return __bfloat162float(h);
}
// pack 2 floats -> 2 bf16 in one u32 (v_cvt_pk_bf16_f32); a->lo, b->hi
__device__ __forceinline__ unsigned pkbf(float a, float b) {
  __hip_bfloat162 h = __float22bfloat162_rn(float2{a, b});
  unsigned u; __builtin_memcpy(&u, &h, 4); return u;
}
__device__ __forceinline__ s16x8 mkfrag(uint2 a, uint2 b) {
  union { unsigned u[4]; s16x8 s; } x;
  x.u[0] = a.x; x.u[1] = a.y; x.u[2] = b.x; x.u[3] = b.y;
  return x.s;
}
__device__ __forceinline__ unsigned mk2(int x, int y) {
  return (x ? 0xFFFFu : 0u) | (y ? 0xFFFF0000u : 0u);
}
// sum of the two bf16 values packed in u (as f32)
__device__ __forceinline__ float upk(unsigned u) {
  return __uint_as_float(u << 16) + __uint_as_float(u & 0xFFFF0000u);
}

__global__ __launch_bounds__(256) void gat_proj(const float* __restrict__ feat,
                                                const float* __restrict__ W,
                                                short* __restrict__ Wh,
                                                short* __restrict__ WhT) {
  __shared__ __align__(16) short ftile[64][136];  // 64 rows x 128 f (pad 8)
  const int tid = threadIdx.x;
  const int w = tid >> 6;            // wave = head
  const int l = tid & 63;
  const int ln = l & 15, lg = l >> 4, g4 = (l >> 4) * 4;
  const int row0 = blockIdx.x * 64;  // flat row in [B*S]
  const int b = row0 >> 11;
  const int sl0 = row0 & (S - 1);

#pragma unroll
  for (int i = 0; i < 4; ++i) {
    int c = i * 256 + tid;           // 8-float chunk
    int r = c >> 4, c8 = (c & 15) * 8;
    const float* src = feat + (size_t)(row0 + r) * F + c8;
    float4 v0 = *(const float4*)src;
    float4 v1 = *(const float4*)(src + 4);
    s16x8 v;
    v[0]=f2bf(v0.x); v[1]=f2bf(v0.y); v[2]=f2bf(v0.z); v[3]=f2bf(v0.w);
    v[4]=f2bf(v1.x); v[5]=f2bf(v1.y); v[6]=f2bf(v1.z); v[7]=f2bf(v1.w);
    *(s16x8*)&ftile[r][c8] = v;
  }

  s16x8 bfr[4][2];
#pragma unroll
  for (int ks = 0; ks < 4; ++ks)
#pragma unroll
    for (int nt = 0; nt < 2; ++nt) {
      s16x8 v;
#pragma unroll
      for (int j = 0; j < 8; ++j)
        v[j] = f2bf(W[((size_t)w * F + ks*32 + lg*8 + j) * D + nt*16 + ln]);
      bfr[ks][nt] = v;
    }
  __syncthreads();

  const f32x4 z4 = {0.f, 0.f, 0.f, 0.f};
#pragma unroll
  for (int mt = 0; mt < 4; ++mt) {
    s16x8 a[4];
#pragma unroll
    for (int ks = 0; ks < 4; ++ks)
      a[ks] = *(const s16x8*)&ftile[mt*16 + ln][ks*32 + lg*8];
#pragma unroll
    for (int nt = 0; nt < 2; ++nt) {
      f32x4 c = z4;
#pragma unroll
      for (int ks = 0; ks < 4; ++ks)
        c = __builtin_amdgcn_mfma_f32_16x16x32_bf16(a[ks], bfr[ks][nt], c, 0, 0, 0);
      s16x4 tv;
#pragma unroll
      for (int r = 0; r < 4; ++r) {
        tv[r] = f2bf(c[r]);
        int srow = row0 + mt*16 + g4 + r;
        int s = srow & (S - 1);
        Wh[(((size_t)b * H + w) * S + s) * D + nt*16 + ln] = tv[r];
      }
      *(s16x4*)&WhT[(((size_t)b * H + w) * D + nt*16 + ln) * S + sl0 + mt*16 + g4] = tv;
    }
  }
}

__global__ __launch_bounds__(64) void gat_attn(const int* __restrict__ adj,
                                               const short* __restrict__ Wh,
                                               const short* __restrict__ WhT,
                                               float* __restrict__ out,
                                               float* __restrict__ PO,
                                               float* __restrict__ PS,
                                               int tiles) {
  const int l = threadIdx.x;
  const int ln = l & 15, lg = l >> 4;

  // XCD-chunked bijective swizzle (grid % 8 == 0)
  const int N = gridDim.x;
  const int rbid = ((int)blockIdx.x & 7) * (N >> 3) + ((int)blockIdx.x >> 3);
  const int c = rbid >> 10;          // t-chunk (1024 waves per chunk)
  const int g = rbid & 1023;
  const int b = g >> 7;
  const int s0 = (g & 127) * 16;     // this wave's 16 q-rows
  const int it0 = c * tiles;

  // adj per-lane: row s0+ln, int4-granules at t = {8lg..+7} U {32+8lg..+7}
  const int4* adjL = (const int4*)(adj + (size_t)b * S * S + (size_t)(s0 + ln) * S);
  const int aoff = 2 * lg;           // int4 units within a 16-int4 tile row

  // Permuted K-row offsets (A row = ln): t = 32(mt>>1) + 8(ln>>2) + 4(mt&1) + (ln&3)
  int toff[4];
#pragma unroll
  for (int mt = 0; mt < 4; ++mt)
    toff[mt] = 32*(mt >> 1) + 8*(ln >> 2) + 4*(mt & 1) + (ln & 3);

  // per-head base pointers (wave-uniform)
  const short* WhH[H];
  const short* WhTH[H];
#pragma unroll
  for (int h = 0; h < H; ++h) {
    WhH[h]  = Wh  + ((size_t)b * H + h) * S * D;
    WhTH[h] = WhT + ((size_t)b * H + h) * D * S;
  }

  // Q fragments per head (B-operand), prescaled by log2(e)/sqrt(D)
  const float cs = 0.25503486f;
  s16x8 qf[H];
#pragma unroll
  for (int h = 0; h < H; ++h) {
    s16x8 v = *(const s16x8*)&WhH[h][(size_t)(s0 + ln) * D + lg*8];
    s16x8 o;
#pragma unroll
    for (int j = 0; j < 8; ++j) o[j] = f2bf(bf2f(v[j]) * cs);
    qf[h] = o;
  }

  const f32x4 z4 = {0.f, 0.f, 0.f, 0.f};
  f32x4 accO[H][2];                  // [h][dt] of O^T (cols = 16 q)
  float psum[H] = {0.f, 0.f, 0.f, 0.f};
#pragma unroll
  for (int h = 0; h < H; ++h) { accO[h][0] = z4; accO[h][1] = z4; }

  // ---- prologue: tile it0 masks + head-0 K/V frags ----
  unsigned m[8];
  {
    const int base = it0 * 16 + aoff;
    int4 a0 = adjL[base], a1 = adjL[base + 1];
    int4 a2 = adjL[base + 8], a3 = adjL[base + 9];
    m[0] = mk2(a0.x, a0.y); m[1] = mk2(a0.z, a0.w);
    m[2] = mk2(a1.x, a1.y); m[3] = mk2(a1.z, a1.w);
    m[4] = mk2(a2.x, a2.y); m[5] = mk2(a2.z, a2.w);
    m[6] = mk2(a3.x, a3.y); m[7] = mk2(a3.z, a3.w);
  }
  s16x8 kf[4];                       // permuted K rows (current head-phase)
  s16x8 av[2][2];                    // V^T A-frags [dt][kt] (current head-phase)
  {
    const size_t t0 = (size_t)it0 * 64;
#pragma unroll
    for (int mt = 0; mt < 4; ++mt)
      kf[mt] = *(const s16x8*)&WhH[0][(t0 + toff[mt]) * D + lg*8];
#pragma unroll
    for (int dt = 0; dt < 2; ++dt)
#pragma unroll
      for (int kt = 0; kt < 2; ++kt)
        av[dt][kt] = *(const s16x8*)&WhTH[0][(size_t)(dt*16 + ln) * S + t0 + kt*32 + lg*8];
  }

#pragma unroll 1
  for (int i = 0; i < tiles; ++i) {
    const int iLd = (i + 1 < tiles) ? i + 1 : i;
    const size_t tc = (size_t)(it0 + i) * 64;
    const size_t tn = (size_t)(it0 + iLd) * 64;

    // issue next-tile adj loads (one full iteration of cover, no barrier drain)
    const int anb = (it0 + iLd) * 16 + aoff;
    int4 a0n = adjL[anb],     a1n = adjL[anb + 1];
    int4 a2n = adjL[anb + 8], a3n = adjL[anb + 9];

#pragma unroll
    for (int h = 0; h < H; ++h) {
      // QK^T (permuted rows): C[t][q], lane: q=ln, t=tb(mt)+r
      f32x4 sv[4];
#pragma unroll
      for (int mt = 0; mt < 4; ++mt)
        sv[mt] = __builtin_amdgcn_mfma_f32_16x16x32_bf16(kf[mt], qf[h], z4, 0, 0, 0);

      // kf dead -> reload for next head-phase (or head 0 of next tile)
      {
        const short* kb = (h < 3) ? WhH[h + 1] : WhH[0];
        const size_t tk = (h < 3) ? tc : tn;
#pragma unroll
        for (int mt = 0; mt < 4; ++mt)
          kf[mt] = *(const s16x8*)&kb[(tk + toff[mt]) * D + lg*8];
      }

      // softmax (fixed max=0) + mask-AND; registers become PV B-frags
      uint2 pks[4];
#pragma unroll
      for (int mt = 0; mt < 4; ++mt) {
        uint2 pk;
        pk.x = pkbf(__builtin_amdgcn_exp2f(sv[mt][0]),
                    __builtin_amdgcn_exp2f(sv[mt][1])) & m[2*mt];
        pk.y = pkbf(__builtin_amdgcn_exp2f(sv[mt][2]),
                    __builtin_amdgcn_exp2f(sv[mt][3])) & m[2*mt + 1];
        psum[h] += upk(pk.x) + upk(pk.y);
        pks[mt] = pk;
      }
      s16x8 ap[2];
#pragma unroll
      for (int kt = 0; kt < 2; ++kt)
        ap[kt] = mkfrag(pks[2*kt], pks[2*kt + 1]);

      // swapped PV: O^T[d][q] += V^T[d][t] * P[q][t]
#pragma unroll
      for (int dt = 0; dt < 2; ++dt)
#pragma unroll
        for (int kt = 0; kt < 2; ++kt)
          accO[h][dt] = __builtin_amdgcn_mfma_f32_16x16x32_bf16(
              av[dt][kt], ap[kt], accO[h][dt], 0, 0, 0);

      // av dead -> reload for next head-phase (or head 0 of next tile)
      {
        const short* vb = (h < 3) ? WhTH[h + 1] : WhTH[0];
        const size_t tv = (h < 3) ? tc : tn;
#pragma unroll
        for (int dt = 0; dt < 2; ++dt)
#pragma unroll
          for (int kt = 0; kt < 2; ++kt)
            av[dt][kt] = *(const s16x8*)&vb[(size_t)(dt*16 + ln) * S + tv + kt*32 + lg*8];
      }
    }

    // convert next-tile masks (after last use of current ones)
    m[0] = mk2(a0n.x, a0n.y); m[1] = mk2(a0n.z, a0n.w);
    m[2] = mk2(a1n.x, a1n.y); m[3] = mk2(a1n.z, a1n.w);
    m[4] = mk2(a2n.x, a2n.y); m[5] = mk2(a2n.z, a2n.w);
    m[6] = mk2(a3n.x, a3n.y); m[7] = mk2(a3n.z, a3n.w);
  }

  // ---- epilogue: reduce psum over the 4 lg-groups (t-slices) ----
#pragma unroll
  for (int h = 0; h < H; ++h) {
    psum[h] += __shfl_xor(psum[h], 16, 64);
    psum[h] += __shfl_xor(psum[h], 32, 64);
  }

  if (PO == nullptr) {
#pragma unroll
    for (int h = 0; h < H; ++h) {
      float inv = 1.0f / psum[h];
#pragma unroll
      for (int dt = 0; dt < 2; ++dt) {
        f32x4 o;
#pragma unroll
        for (int r = 0; r < 4; ++r) o[r] = accO[h][dt][r] * inv;
        *(f32x4*)&out[((size_t)b * S + s0 + ln) * (H * D) + h*32 + dt*16 + 4*lg] = o;
      }
    }
  } else {
    float* po = PO + (size_t)rbid * 2048;
#pragma unroll
    for (int h = 0; h < H; ++h) {
#pragma unroll
      for (int dt = 0; dt < 2; ++dt)
        *(f32x4*)&po[ln*128 + h*32 + dt*16 + 4*lg] = accO[h][dt];
      if (lg == 0) PS[(size_t)rbid * 64 + h*16 + ln] = psum[h];
    }
  }
}

__global__ __launch_bounds__(256) void gat_reduce(const float* __restrict__ PO,
                                                  const float* __restrict__ PS,
                                                  float* __restrict__ out,
                                                  int nchunks) {
  const int f4 = blockIdx.x * 256 + threadIdx.x;  // f32x4 index over out
  const int d4 = f4 & 31;            // 32 f32x4 per s-row (128 floats)
  const int h = d4 >> 3;
  const int s_flat = f4 >> 5;        // b*2048 + s
  const int b = s_flat >> 11, s = s_flat & 2047;
  const int s16 = s >> 4, q = s & 15;

  f32x4 acc = {0.f, 0.f, 0.f, 0.f};
  float ps = 0.f;
  for (int c = 0; c < nchunks; ++c) {
    size_t rbid = (size_t)c * 1024 + b * 128 + s16;
    acc += *(const f32x4*)&PO[rbid * 2048 + q*128 + d4*4];
    ps += PS[rbid * 64 + h*16 + q];
  }
  float inv = 1.0f / ps;
  f32x4 o = acc * inv;
  *(f32x4*)&out[(size_t)f4 * 4] = o;
}

}  // namespace

extern "C" void kernel_launch(void* const* d_in, const int* in_sizes, int n_in,
                              void* d_out, int out_size, void* d_ws, size_t ws_size,
                              hipStream_t stream) {
  const float* feat = (const float*)d_in[0];   // [8,2048,128] f32
  const int* adj    = (const int*)d_in[1];     // [8,2048,2048] i32
  const float* W    = (const float*)d_in[2];   // [4,128,32] f32
  float* out        = (float*)d_out;           // [8,2048,128] f32

  short* Wh  = (short*)d_ws;                             // 4 MiB bf16
  short* WhT = Wh + (size_t)8 * H * S * D;               // 4 MiB bf16
  const size_t whbytes = (size_t)2 * 8 * H * S * D * sizeof(short);
  const size_t chunkPO = (size_t)1024 * 2048 * sizeof(float);  // 8 MiB
  const size_t chunkPS = (size_t)1024 * 64 * sizeof(float);    // 256 KiB

  int nchunks = 1;
  if (ws_size >= whbytes + 4 * (chunkPO + chunkPS)) nchunks = 4;
  else if (ws_size >= whbytes + 2 * (chunkPO + chunkPS)) nchunks = 2;

  float* PO = nullptr;
  float* PS = nullptr;
  if (nchunks > 1) {
    PO = (float*)((char*)d_ws + whbytes);
    PS = (float*)((char*)d_ws + whbytes + (size_t)nchunks * chunkPO);
  }

  gat_proj<<<(8 * S) / 64, 256, 0, stream>>>(feat, W, Wh, WhT);
  gat_attn<<<1024 * nchunks, 64, 0, stream>>>(adj, Wh, WhT, out, PO, PS, 32 / nchunks);
  if (nchunks > 1) gat_reduce<<<2048, 256, 0, stream>>>(PO, PS, out, nchunks);
}

// Round 10
// 85.929 us; speedup vs baseline: 1.4907x; 1.4907x over previous
//
#include <hip/hip_runtime.h>
#include <hip/hip_bf16.h>
#include <stdint.h>

// GraphAttentionLayer: B=8, S=2048, F=128, H=4, D=32
// proj: Wh[b,h,s,d] (row-major) AND WhT[b,h,d,s] (transposed) via bf16 MFMA
// attn: block = (b, h, 128 q-rows, t-chunk) = 8 waves x 16 q-rows.
//   K-tile + V^T-tile staged to LDS ONCE per block-iter (XOR-swizzled,
//   <=2-way banks), shared by all 8 waves. adj per-lane global->reg.
//   Permuted-K QK^T so softmax registers ARE the PV B-frags; ones-MFMA rowsum.

namespace {
constexpr int S = 2048;
constexpr int F = 128;
constexpr int H = 4;
constexpr int D = 32;

typedef __attribute__((ext_vector_type(4))) float f32x4;
typedef __attribute__((ext_vector_type(8))) short s16x8;
typedef __attribute__((ext_vector_type(4))) short s16x4;

__device__ __forceinline__ short f2bf(float f) {
  __hip_bfloat16 h = __float2bfloat16(f);
  short s; __builtin_memcpy(&s, &h, sizeof(s)); return s;
}
__device__ __forceinline__ float bf2f(short s) {
  __hip_bfloat16 h; __builtin_memcpy(&h, &s, sizeof(s));
  return __bfloat162float(h);
}
__device__ __forceinline__ unsigned pkbf(float a, float b) {
  __hip_bfloat162 h = __float22bfloat162_rn(float2{a, b});
  unsigned u; __builtin_memcpy(&u, &h, 4); return u;
}
__device__ __forceinline__ s16x8 mkfrag(uint2 a, uint2 b) {
  union { unsigned u[4]; s16x8 s; } x;
  x.u[0] = a.x; x.u[1] = a.y; x.u[2] = b.x; x.u[3] = b.y;
  return x.s;
}
__device__ __forceinline__ unsigned mk2(int x, int y) {
  return (x ? 0xFFFFu : 0u) | (y ? 0xFFFF0000u : 0u);
}

__global__ __launch_bounds__(256) void gat_proj(const float* __restrict__ feat,
                                                const float* __restrict__ W,
                                                short* __restrict__ Wh,
                                                short* __restrict__ WhT) {
  __shared__ __align__(16) short ftile[64][136];  // 64 rows x 128 f (pad 8)
  const int tid = threadIdx.x;
  const int w = tid >> 6;            // wave = head
  const int l = tid & 63;
  const int ln = l & 15, lg = l >> 4, g4 = (l >> 4) * 4;
  const int row0 = blockIdx.x * 64;  // flat row in [B*S]
  const int b = row0 >> 11;
  const int sl0 = row0 & (S - 1);

#pragma unroll
  for (int i = 0; i < 4; ++i) {
    int c = i * 256 + tid;           // 8-float chunk
    int r = c >> 4, c8 = (c & 15) * 8;
    const float* src = feat + (size_t)(row0 + r) * F + c8;
    float4 v0 = *(const float4*)src;
    float4 v1 = *(const float4*)(src + 4);
    s16x8 v;
    v[0]=f2bf(v0.x); v[1]=f2bf(v0.y); v[2]=f2bf(v0.z); v[3]=f2bf(v0.w);
    v[4]=f2bf(v1.x); v[5]=f2bf(v1.y); v[6]=f2bf(v1.z); v[7]=f2bf(v1.w);
    *(s16x8*)&ftile[r][c8] = v;
  }

  s16x8 bfr[4][2];
#pragma unroll
  for (int ks = 0; ks < 4; ++ks)
#pragma unroll
    for (int nt = 0; nt < 2; ++nt) {
      s16x8 v;
#pragma unroll
      for (int j = 0; j < 8; ++j)
        v[j] = f2bf(W[((size_t)w * F + ks*32 + lg*8 + j) * D + nt*16 + ln]);
      bfr[ks][nt] = v;
    }
  __syncthreads();

  const f32x4 z4 = {0.f, 0.f, 0.f, 0.f};
#pragma unroll
  for (int mt = 0; mt < 4; ++mt) {
    s16x8 a[4];
#pragma unroll
    for (int ks = 0; ks < 4; ++ks)
      a[ks] = *(const s16x8*)&ftile[mt*16 + ln][ks*32 + lg*8];
#pragma unroll
    for (int nt = 0; nt < 2; ++nt) {
      f32x4 c = z4;
#pragma unroll
      for (int ks = 0; ks < 4; ++ks)
        c = __builtin_amdgcn_mfma_f32_16x16x32_bf16(a[ks], bfr[ks][nt], c, 0, 0, 0);
      s16x4 tv;
#pragma unroll
      for (int r = 0; r < 4; ++r) {
        tv[r] = f2bf(c[r]);
        int srow = row0 + mt*16 + g4 + r;
        int s = srow & (S - 1);
        Wh[(((size_t)b * H + w) * S + s) * D + nt*16 + ln] = tv[r];
      }
      *(s16x4*)&WhT[(((size_t)b * H + w) * D + nt*16 + ln) * S + sl0 + mt*16 + g4] = tv;
    }
  }
}

__global__ __launch_bounds__(512) void gat_attn(const int* __restrict__ adj,
                                                const short* __restrict__ Wh,
                                                const short* __restrict__ WhT,
                                                float* __restrict__ out,
                                                float* __restrict__ PO,
                                                float* __restrict__ PS,
                                                int tiles) {
  // K tile [64 t][64B] + V^T tile [32 d][128B], XOR-swizzled, double-buffered
  __shared__ __align__(16) char kv[2][8192];

  const int tid = threadIdx.x;
  const int ww = tid >> 6;           // wave 0..7
  const int l = tid & 63;
  const int ln = l & 15, lg = l >> 4;

  // XCD-chunked bijective swizzle (grid % 8 == 0)
  const int N = gridDim.x;
  const int rbid = ((int)blockIdx.x & 7) * (N >> 3) + ((int)blockIdx.x >> 3);
  const int c = rbid >> 9;           // t-chunk
  const int rem = rbid & 511;
  const int b = rem >> 6;
  const int h = (rem >> 4) & 3;
  const int qg = rem & 15;
  const int q0 = qg * 128 + ww * 16; // this wave's q-rows: q0 + ln
  const int it0 = c * tiles;

  const short* WhBH = Wh + ((size_t)b * H + h) * S * D;
  const short* WhTBH = WhT + ((size_t)b * H + h) * D * S;
  const int4* adjL = (const int4*)(adj + (size_t)b * S * S + (size_t)(q0 + ln) * S);

  // ---- staging role (wave-uniform): ww<4 -> K chunk ww; else V^T chunk ww-4
  const char* stgSrc;                // per-tile stride differs per role
  int stgLds;                        // LDS byte offset (iteration-invariant)
  size_t stgStride;
  if (ww < 4) {
    stgSrc = (const char*)WhBH + ww*1024 + l*16;
    stgStride = 4096;                // K tile = 4KB contiguous
    int row = ww*16 + (l >> 2), db = l & 3;
    stgLds = row*64 + 16*(db ^ ((row & 3) ^ ((row >> 3) & 3)));
  } else {
    int d = (ww - 4)*8 + (l >> 3);
    stgSrc = (const char*)WhTBH + (size_t)d * S * 2 + (l & 7) * 16;
    stgStride = 128;                 // V^T: 64 t = 128B per row per tile
    stgLds = 4096 + d*128 + 16*((l & 7) ^ (d & 7));
  }

  // ---- LDS read offsets (iteration-invariant)
  const int kswz = (ln & 3) ^ (ln >> 2);
  int koff[4];
#pragma unroll
  for (int mt = 0; mt < 4; ++mt) {
    int lrow = 32*(mt >> 1) + 8*(ln >> 2) + 4*(mt & 1) + (ln & 3);
    koff[mt] = lrow*64 + 16*(lg ^ kswz);
  }
  int voff[2][2];
#pragma unroll
  for (int dt = 0; dt < 2; ++dt)
#pragma unroll
    for (int kt = 0; kt < 2; ++kt)
      voff[dt][kt] = 4096 + (dt*16 + ln)*128 + 16*((4*kt + lg) ^ (ln & 7));

  // Q fragment (B-operand of swapped QK^T), prescaled by log2(e)/sqrt(D)
  const float cs = 0.25503486f;
  s16x8 qf;
  {
    s16x8 v = *(const s16x8*)&WhBH[(size_t)(q0 + ln) * D + lg*8];
#pragma unroll
    for (int j = 0; j < 8; ++j) qf[j] = f2bf(bf2f(v[j]) * cs);
  }
  s16x8 onesf;
#pragma unroll
  for (int j = 0; j < 8; ++j) onesf[j] = (short)0x3F80;

  const f32x4 z4 = {0.f, 0.f, 0.f, 0.f};
  f32x4 accO[2];                     // [dt] of O^T (cols = 16 q)
  f32x4 accP = z4;                   // rowsum (all 4 regs identical)
  accO[0] = z4; accO[1] = z4;

  // ---- prologue: stage tile it0, masks tile it0 ----
  unsigned m[8];
  {
    s16x8 stg = *(const s16x8*)(stgSrc + (size_t)it0 * stgStride);
    const int ab = it0 * 16 + 2*lg;
    int4 a0 = adjL[ab], a1 = adjL[ab + 1];
    int4 a2 = adjL[ab + 8], a3 = adjL[ab + 9];
    *(s16x8*)(&kv[0][0] + stgLds) = stg;
    m[0] = mk2(a0.x, a0.y); m[1] = mk2(a0.z, a0.w);
    m[2] = mk2(a1.x, a1.y); m[3] = mk2(a1.z, a1.w);
    m[4] = mk2(a2.x, a2.y); m[5] = mk2(a2.z, a2.w);
    m[6] = mk2(a3.x, a3.y); m[7] = mk2(a3.z, a3.w);
  }
  __syncthreads();

#pragma unroll 1
  for (int i = 0; i < tiles; ++i) {
    const int cur = i & 1, nxt = cur ^ 1;
    const int iLd = (i + 1 < tiles) ? i + 1 : i;

    // issue next-tile loads early (full-body latency cover)
    s16x8 stg = *(const s16x8*)(stgSrc + (size_t)(it0 + iLd) * stgStride);
    const int ab = (it0 + iLd) * 16 + 2*lg;
    int4 a0n = adjL[ab],     a1n = adjL[ab + 1];
    int4 a2n = adjL[ab + 8], a3n = adjL[ab + 9];

    // QK^T from LDS (permuted K rows)
    const char* kb = &kv[cur][0];
    f32x4 sv[4];
#pragma unroll
    for (int mt = 0; mt < 4; ++mt) {
      s16x8 kf = *(const s16x8*)(kb + koff[mt]);
      sv[mt] = __builtin_amdgcn_mfma_f32_16x16x32_bf16(kf, qf, z4, 0, 0, 0);
    }

    // softmax (fixed max=0) + mask-AND; registers become PV B-frags
    uint2 pks[4];
#pragma unroll
    for (int mt = 0; mt < 4; ++mt) {
      uint2 pk;
      pk.x = pkbf(__builtin_amdgcn_exp2f(sv[mt][0]),
                  __builtin_amdgcn_exp2f(sv[mt][1])) & m[2*mt];
      pk.y = pkbf(__builtin_amdgcn_exp2f(sv[mt][2]),
                  __builtin_amdgcn_exp2f(sv[mt][3])) & m[2*mt + 1];
      pks[mt] = pk;
    }
    s16x8 ap[2];
#pragma unroll
    for (int kt = 0; kt < 2; ++kt)
      ap[kt] = mkfrag(pks[2*kt], pks[2*kt + 1]);

    // swapped PV from LDS V^T + rowsum via ones-MFMA
#pragma unroll
    for (int dt = 0; dt < 2; ++dt)
#pragma unroll
      for (int kt = 0; kt < 2; ++kt) {
        s16x8 av = *(const s16x8*)(kb + voff[dt][kt]);
        accO[dt] = __builtin_amdgcn_mfma_f32_16x16x32_bf16(av, ap[kt], accO[dt], 0, 0, 0);
      }
#pragma unroll
    for (int kt = 0; kt < 2; ++kt)
      accP = __builtin_amdgcn_mfma_f32_16x16x32_bf16(onesf, ap[kt], accP, 0, 0, 0);

    // commit next tile: stage write + mask convert
    *(s16x8*)(&kv[nxt][0] + stgLds) = stg;
    m[0] = mk2(a0n.x, a0n.y); m[1] = mk2(a0n.z, a0n.w);
    m[2] = mk2(a1n.x, a1n.y); m[3] = mk2(a1n.z, a1n.w);
    m[4] = mk2(a2n.x, a2n.y); m[5] = mk2(a2n.z, a2n.w);
    m[6] = mk2(a3n.x, a3n.y); m[7] = mk2(a3n.z, a3n.w);
    __syncthreads();
  }

  // ---- epilogue: per-lane denominator in accP[0] ----
  if (PO == nullptr) {
    float inv = 1.0f / accP[0];
#pragma unroll
    for (int dt = 0; dt < 2; ++dt) {
      f32x4 o;
#pragma unroll
      for (int r = 0; r < 4; ++r) o[r] = accO[dt][r] * inv;
      *(f32x4*)&out[((size_t)b * S + q0 + ln) * (H * D) + h*32 + dt*16 + 4*lg] = o;
    }
  } else {
    float* po = PO + (size_t)rbid * 4096;
#pragma unroll
    for (int dt = 0; dt < 2; ++dt)
      *(f32x4*)&po[(ww*16 + ln)*32 + dt*16 + 4*lg] = accO[dt];
    if (lg == 0) PS[(size_t)rbid * 128 + ww*16 + ln] = accP[0];
  }
}

__global__ __launch_bounds__(256) void gat_reduce(const float* __restrict__ PO,
                                                  const float* __restrict__ PS,
                                                  float* __restrict__ out,
                                                  int nchunks) {
  const int f4 = blockIdx.x * 256 + threadIdx.x;  // f32x4 index over out
  const int d4 = f4 & 31;            // 32 f32x4 per s-row (128 floats)
  const int h = d4 >> 3;
  const int dq = d4 & 7;
  const int s_flat = f4 >> 5;        // b*2048 + s
  const int b = s_flat >> 11, s = s_flat & 2047;
  const int qg = s >> 7, ql = s & 127;

  f32x4 acc = {0.f, 0.f, 0.f, 0.f};
  float ps = 0.f;
  for (int c = 0; c < nchunks; ++c) {
    size_t base = (size_t)(c * 512 + b * 64 + h * 16 + qg);
    acc += *(const f32x4*)&PO[base * 4096 + ql*32 + dq*4];
    ps += PS[base * 128 + ql];
  }
  float inv = 1.0f / ps;
  f32x4 o = acc * inv;
  *(f32x4*)&out[(size_t)f4 * 4] = o;
}

}  // namespace

extern "C" void kernel_launch(void* const* d_in, const int* in_sizes, int n_in,
                              void* d_out, int out_size, void* d_ws, size_t ws_size,
                              hipStream_t stream) {
  const float* feat = (const float*)d_in[0];   // [8,2048,128] f32
  const int* adj    = (const int*)d_in[1];     // [8,2048,2048] i32
  const float* W    = (const float*)d_in[2];   // [4,128,32] f32
  float* out        = (float*)d_out;           // [8,2048,128] f32

  short* Wh  = (short*)d_ws;                             // 4 MiB bf16
  short* WhT = Wh + (size_t)8 * H * S * D;               // 4 MiB bf16
  const size_t whbytes = (size_t)2 * 8 * H * S * D * sizeof(short);
  const size_t chunkPO = (size_t)512 * 4096 * sizeof(float);   // 8 MiB
  const size_t chunkPS = (size_t)512 * 128 * sizeof(float);    // 256 KiB

  int nchunks = 1;
  if (ws_size >= whbytes + 2 * (chunkPO + chunkPS)) nchunks = 2;

  float* PO = nullptr;
  float* PS = nullptr;
  if (nchunks > 1) {
    PO = (float*)((char*)d_ws + whbytes);
    PS = (float*)((char*)d_ws + whbytes + (size_t)nchunks * chunkPO);
  }

  gat_proj<<<(8 * S) / 64, 256, 0, stream>>>(feat, W, Wh, WhT);
  gat_attn<<<512 * nchunks, 512, 0, stream>>>(adj, Wh, WhT, out, PO, PS, 32 / nchunks);
  if (nchunks > 1) gat_reduce<<<2048, 256, 0, stream>>>(PO, PS, out, nchunks);
}

// Round 11
// 71.310 us; speedup vs baseline: 1.7963x; 1.2050x over previous
//
#include <hip/hip_runtime.h>
#include <hip/hip_bf16.h>
#include <stdint.h>

// GraphAttentionLayer: B=8, S=2048, F=128, H=4, D=32
// proj: Wh[b,h,s,d] (row-major) AND WhT[b,h,d,s] (transposed) via bf16 MFMA
// attn: block = (b, h, 64 q-rows, t-chunk) = 4 waves x 16 q-rows.
//   adj tile read COALESCED (dense 1KB/wave instructions), converted to packed
//   u16 masks at stage time, redistributed through XOR-swizzled LDS (<=2-way).
//   K / V^T tiles LDS-shared. Permuted-K QK^T so softmax registers ARE the PV
//   B-fragments; ones-MFMA rowsum; fixed-max softmax (max=0).

namespace {
constexpr int S = 2048;
constexpr int F = 128;
constexpr int H = 4;
constexpr int D = 32;

typedef __attribute__((ext_vector_type(4))) float f32x4;
typedef __attribute__((ext_vector_type(8))) short s16x8;
typedef __attribute__((ext_vector_type(4))) short s16x4;

__device__ __forceinline__ short f2bf(float f) {
  __hip_bfloat16 h = __float2bfloat16(f);
  short s; __builtin_memcpy(&s, &h, sizeof(s)); return s;
}
__device__ __forceinline__ float bf2f(short s) {
  __hip_bfloat16 h; __builtin_memcpy(&h, &s, sizeof(s));
  return __bfloat162float(h);
}
__device__ __forceinline__ unsigned pkbf(float a, float b) {
  __hip_bfloat162 h = __float22bfloat162_rn(float2{a, b});
  unsigned u; __builtin_memcpy(&u, &h, 4); return u;
}
__device__ __forceinline__ s16x8 mkfrag(uint2 a, uint2 b) {
  union { unsigned u[4]; s16x8 s; } x;
  x.u[0] = a.x; x.u[1] = a.y; x.u[2] = b.x; x.u[3] = b.y;
  return x.s;
}
__device__ __forceinline__ unsigned mk2(int x, int y) {
  return (x ? 0xFFFFu : 0u) | (y ? 0xFFFF0000u : 0u);
}

__global__ __launch_bounds__(256) void gat_proj(const float* __restrict__ feat,
                                                const float* __restrict__ W,
                                                short* __restrict__ Wh,
                                                short* __restrict__ WhT) {
  __shared__ __align__(16) short ftile[64][136];  // 64 rows x 128 f (pad 8)
  const int tid = threadIdx.x;
  const int w = tid >> 6;            // wave = head
  const int l = tid & 63;
  const int ln = l & 15, lg = l >> 4, g4 = (l >> 4) * 4;
  const int row0 = blockIdx.x * 64;  // flat row in [B*S]
  const int b = row0 >> 11;
  const int sl0 = row0 & (S - 1);

#pragma unroll
  for (int i = 0; i < 4; ++i) {
    int c = i * 256 + tid;           // 8-float chunk
    int r = c >> 4, c8 = (c & 15) * 8;
    const float* src = feat + (size_t)(row0 + r) * F + c8;
    float4 v0 = *(const float4*)src;
    float4 v1 = *(const float4*)(src + 4);
    s16x8 v;
    v[0]=f2bf(v0.x); v[1]=f2bf(v0.y); v[2]=f2bf(v0.z); v[3]=f2bf(v0.w);
    v[4]=f2bf(v1.x); v[5]=f2bf(v1.y); v[6]=f2bf(v1.z); v[7]=f2bf(v1.w);
    *(s16x8*)&ftile[r][c8] = v;
  }

  s16x8 bfr[4][2];
#pragma unroll
  for (int ks = 0; ks < 4; ++ks)
#pragma unroll
    for (int nt = 0; nt < 2; ++nt) {
      s16x8 v;
#pragma unroll
      for (int j = 0; j < 8; ++j)
        v[j] = f2bf(W[((size_t)w * F + ks*32 + lg*8 + j) * D + nt*16 + ln]);
      bfr[ks][nt] = v;
    }
  __syncthreads();

  const f32x4 z4 = {0.f, 0.f, 0.f, 0.f};
#pragma unroll
  for (int mt = 0; mt < 4; ++mt) {
    s16x8 a[4];
#pragma unroll
    for (int ks = 0; ks < 4; ++ks)
      a[ks] = *(const s16x8*)&ftile[mt*16 + ln][ks*32 + lg*8];
#pragma unroll
    for (int nt = 0; nt < 2; ++nt) {
      f32x4 c = z4;
#pragma unroll
      for (int ks = 0; ks < 4; ++ks)
        c = __builtin_amdgcn_mfma_f32_16x16x32_bf16(a[ks], bfr[ks][nt], c, 0, 0, 0);
      s16x4 tv;
#pragma unroll
      for (int r = 0; r < 4; ++r) {
        tv[r] = f2bf(c[r]);
        int srow = row0 + mt*16 + g4 + r;
        int s = srow & (S - 1);
        Wh[(((size_t)b * H + w) * S + s) * D + nt*16 + ln] = tv[r];
      }
      *(s16x4*)&WhT[(((size_t)b * H + w) * D + nt*16 + ln) * S + sl0 + mt*16 + g4] = tv;
    }
  }
}

__global__ __launch_bounds__(256, 4) void gat_attn(const int* __restrict__ adj,
                                                   const short* __restrict__ Wh,
                                                   const short* __restrict__ WhT,
                                                   float* __restrict__ out,
                                                   float* __restrict__ PO,
                                                   float* __restrict__ PS,
                                                   int tiles) {
  // mbuf: u16 masks [64 rows][8 granules x16B, col ^ (row&7)], double-buffered
  // kv:   K [64 t][4 gran x16B, swz] at 0..4095 ; V^T [32 d][8 gran, swz] at 4096..8191
  __shared__ __align__(16) char mbuf[2][8192];
  __shared__ __align__(16) char kv[2][8192];

  const int tid = threadIdx.x;
  const int ww = tid >> 6;           // wave 0..3
  const int l = tid & 63;
  const int ln = l & 15, lg = l >> 4;

  // XCD-chunked bijective swizzle (grid % 8 == 0)
  const int N = gridDim.x;
  const int rbid = ((int)blockIdx.x & 7) * (N >> 3) + ((int)blockIdx.x >> 3);
  const int c = rbid >> 10;          // t-chunk (1024 blocks/chunk)
  const int rem = rbid & 1023;       // b*128 + h*32 + qg
  const int b = rem >> 7;
  const int h = (rem >> 5) & 3;
  const int qg = rem & 31;
  const int qb = qg * 64;            // block q-base (64 rows)
  const int it0 = c * tiles;

  const short* WhBH = Wh + ((size_t)b * H + h) * S * D;
  const short* WhTBH = WhT + ((size_t)b * H + h) * D * S;
  const int* adjB = adj + (size_t)b * S * S;

  // ---- staging sources (coalesced; advance by tile) ----
  // adj: thread covers rows (tid>>4)+16j, int4-granule g4i = tid&15
  const int g4i = tid & 15, ar0 = tid >> 4;
  const int* aSrc = adjB + (size_t)(qb + ar0) * S + 4 * g4i;
  // K: row tid>>2 (linear t), 16B granule tid&3
  const short* kSrc = WhBH + (size_t)(tid >> 2) * D + (tid & 3) * 8;
  // V^T: row d = tid>>3, granule tid&7
  const short* vSrc = WhTBH + (size_t)(tid >> 3) * S + (tid & 7) * 8;

  // ---- staging LDS destinations (iteration-invariant byte offsets) ----
  const int mw0 = ar0*128 + (((g4i >> 1) ^ (ar0 & 7)) << 4) + (g4i & 1) * 8;
  const int kwA = (tid >> 2)*64 +
                  ((((tid & 3) ^ (((tid >> 2) & 3) ^ ((tid >> 5) & 3)))) << 4);
  const int vwA = 4096 + (tid >> 3)*128 + ((((tid & 7) ^ ((tid >> 3) & 7))) << 4);

  // ---- read offsets (iteration-invariant) ----
  const int R = ww*16 + ln;          // this lane's mask row (== q-local)
  const int mr0 = R*128 + ((lg ^ (ln & 7)) << 4);
  const int mr1 = R*128 + (((4 + lg) ^ (ln & 7)) << 4);
  const int kswz = (ln & 3) ^ (ln >> 2);
  int koff[4];
#pragma unroll
  for (int mt = 0; mt < 4; ++mt) {
    int lrow = 32*(mt >> 1) + 8*(ln >> 2) + 4*(mt & 1) + (ln & 3);
    koff[mt] = lrow*64 + ((lg ^ kswz) << 4);
  }
  int voff[2][2];
#pragma unroll
  for (int dt = 0; dt < 2; ++dt)
#pragma unroll
    for (int kt = 0; kt < 2; ++kt)
      voff[dt][kt] = 4096 + (dt*16 + ln)*128 + (((4*kt + lg) ^ (ln & 7)) << 4);

  // Q fragment (B-operand of swapped QK^T), prescaled by log2(e)/sqrt(D)
  const float cs = 0.25503486f;
  s16x8 qf;
  {
    s16x8 v = *(const s16x8*)&WhBH[(size_t)(qb + R) * D + lg*8];
#pragma unroll
    for (int j = 0; j < 8; ++j) qf[j] = f2bf(bf2f(v[j]) * cs);
  }
  s16x8 onesf;
#pragma unroll
  for (int j = 0; j < 8; ++j) onesf[j] = (short)0x3F80;

  const f32x4 z4 = {0.f, 0.f, 0.f, 0.f};
  f32x4 accO[2];                     // [dt] of O^T (cols = 16 q)
  f32x4 accP = z4;
  accO[0] = z4; accO[1] = z4;

  // ---- prologue: stage tile it0 into buffer 0 ----
  {
    const size_t t0i = (size_t)it0 * 64;
#pragma unroll
    for (int j = 0; j < 4; ++j) {
      int4 a = *(const int4*)(aSrc + (size_t)(16*j) * S + t0i);
      *(unsigned*)(&mbuf[0][0] + mw0 + j*2048)     = mk2(a.x, a.y);
      *(unsigned*)(&mbuf[0][0] + mw0 + j*2048 + 4) = mk2(a.z, a.w);
    }
    s16x8 ks = *(const s16x8*)(kSrc + t0i * D);
    s16x8 vs = *(const s16x8*)(vSrc + t0i);
    *(s16x8*)(&kv[0][0] + kwA) = ks;
    *(s16x8*)(&kv[0][0] + vwA) = vs;
  }
  __syncthreads();

#pragma unroll 1
  for (int i = 0; i < tiles; ++i) {
    const int cur = i & 1, nxt = cur ^ 1;
    const int iLd = (i + 1 < tiles) ? i + 1 : i;
    const size_t tni = (size_t)(it0 + iLd) * 64;

    // issue next-tile loads early (coalesced; full-body latency cover)
    int4 an[4];
#pragma unroll
    for (int j = 0; j < 4; ++j)
      an[j] = *(const int4*)(aSrc + (size_t)(16*j) * S + tni);
    s16x8 kstg = *(const s16x8*)(kSrc + tni * D);
    s16x8 vstg = *(const s16x8*)(vSrc + tni);

    // masks for current tile (2 x b128)
    const uint4 mA = *(const uint4*)(&mbuf[cur][0] + mr0);
    const uint4 mB = *(const uint4*)(&mbuf[cur][0] + mr1);

    // QK^T from LDS (permuted K rows)
    const char* kb = &kv[cur][0];
    f32x4 sv[4];
#pragma unroll
    for (int mt = 0; mt < 4; ++mt) {
      s16x8 kf = *(const s16x8*)(kb + koff[mt]);
      sv[mt] = __builtin_amdgcn_mfma_f32_16x16x32_bf16(kf, qf, z4, 0, 0, 0);
    }

    // softmax (fixed max=0) + mask-AND; registers become PV B-frags
    uint2 pks[4];
    pks[0].x = pkbf(__builtin_amdgcn_exp2f(sv[0][0]), __builtin_amdgcn_exp2f(sv[0][1])) & mA.x;
    pks[0].y = pkbf(__builtin_amdgcn_exp2f(sv[0][2]), __builtin_amdgcn_exp2f(sv[0][3])) & mA.y;
    pks[1].x = pkbf(__builtin_amdgcn_exp2f(sv[1][0]), __builtin_amdgcn_exp2f(sv[1][1])) & mA.z;
    pks[1].y = pkbf(__builtin_amdgcn_exp2f(sv[1][2]), __builtin_amdgcn_exp2f(sv[1][3])) & mA.w;
    pks[2].x = pkbf(__builtin_amdgcn_exp2f(sv[2][0]), __builtin_amdgcn_exp2f(sv[2][1])) & mB.x;
    pks[2].y = pkbf(__builtin_amdgcn_exp2f(sv[2][2]), __builtin_amdgcn_exp2f(sv[2][3])) & mB.y;
    pks[3].x = pkbf(__builtin_amdgcn_exp2f(sv[3][0]), __builtin_amdgcn_exp2f(sv[3][1])) & mB.z;
    pks[3].y = pkbf(__builtin_amdgcn_exp2f(sv[3][2]), __builtin_amdgcn_exp2f(sv[3][3])) & mB.w;

    s16x8 ap[2];
#pragma unroll
    for (int kt = 0; kt < 2; ++kt)
      ap[kt] = mkfrag(pks[2*kt], pks[2*kt + 1]);

    // swapped PV from LDS V^T + rowsum via ones-MFMA
#pragma unroll
    for (int dt = 0; dt < 2; ++dt)
#pragma unroll
      for (int kt = 0; kt < 2; ++kt) {
        s16x8 av = *(const s16x8*)(kb + voff[dt][kt]);
        accO[dt] = __builtin_amdgcn_mfma_f32_16x16x32_bf16(av, ap[kt], accO[dt], 0, 0, 0);
      }
#pragma unroll
    for (int kt = 0; kt < 2; ++kt)
      accP = __builtin_amdgcn_mfma_f32_16x16x32_bf16(onesf, ap[kt], accP, 0, 0, 0);

    // commit next tile: convert + write masks, write K/V
#pragma unroll
    for (int j = 0; j < 4; ++j) {
      *(unsigned*)(&mbuf[nxt][0] + mw0 + j*2048)     = mk2(an[j].x, an[j].y);
      *(unsigned*)(&mbuf[nxt][0] + mw0 + j*2048 + 4) = mk2(an[j].z, an[j].w);
    }
    *(s16x8*)(&kv[nxt][0] + kwA) = kstg;
    *(s16x8*)(&kv[nxt][0] + vwA) = vstg;
    __syncthreads();
  }

  // ---- epilogue: per-lane denominator in accP[0] ----
  if (PO == nullptr) {
    float inv = 1.0f / accP[0];
#pragma unroll
    for (int dt = 0; dt < 2; ++dt) {
      f32x4 o;
#pragma unroll
      for (int r = 0; r < 4; ++r) o[r] = accO[dt][r] * inv;
      *(f32x4*)&out[((size_t)b * S + qb + R) * (H * D) + h*32 + dt*16 + 4*lg] = o;
    }
  } else {
    float* po = PO + (size_t)rbid * 2048;
#pragma unroll
    for (int dt = 0; dt < 2; ++dt)
      *(f32x4*)&po[R*32 + dt*16 + 4*lg] = accO[dt];
    if (lg == 0) PS[(size_t)rbid * 64 + R] = accP[0];
  }
}

__global__ __launch_bounds__(256) void gat_reduce(const float* __restrict__ PO,
                                                  const float* __restrict__ PS,
                                                  float* __restrict__ out,
                                                  int nchunks) {
  const int f4 = blockIdx.x * 256 + threadIdx.x;  // f32x4 index over out
  const int d4 = f4 & 31;            // 32 f32x4 per s-row (128 floats)
  const int h = d4 >> 3;
  const int dq = d4 & 7;
  const int s_flat = f4 >> 5;        // b*2048 + s
  const int b = s_flat >> 11, s = s_flat & 2047;
  const int qg = s >> 6, ql = s & 63;

  f32x4 acc = {0.f, 0.f, 0.f, 0.f};
  float ps = 0.f;
  for (int c = 0; c < nchunks; ++c) {
    size_t base = (size_t)c * 1024 + b * 128 + h * 32 + qg;
    acc += *(const f32x4*)&PO[base * 2048 + ql*32 + dq*4];
    ps += PS[base * 64 + ql];
  }
  float inv = 1.0f / ps;
  f32x4 o = acc * inv;
  *(f32x4*)&out[(size_t)f4 * 4] = o;
}

}  // namespace

extern "C" void kernel_launch(void* const* d_in, const int* in_sizes, int n_in,
                              void* d_out, int out_size, void* d_ws, size_t ws_size,
                              hipStream_t stream) {
  const float* feat = (const float*)d_in[0];   // [8,2048,128] f32
  const int* adj    = (const int*)d_in[1];     // [8,2048,2048] i32
  const float* W    = (const float*)d_in[2];   // [4,128,32] f32
  float* out        = (float*)d_out;           // [8,2048,128] f32

  short* Wh  = (short*)d_ws;                             // 4 MiB bf16
  short* WhT = Wh + (size_t)8 * H * S * D;               // 4 MiB bf16
  const size_t whbytes = (size_t)2 * 8 * H * S * D * sizeof(short);
  const size_t chunkPO = (size_t)1024 * 2048 * sizeof(float);  // 8 MiB
  const size_t chunkPS = (size_t)1024 * 64 * sizeof(float);    // 256 KiB

  int nchunks = 1;
  if (ws_size >= whbytes + 2 * (chunkPO + chunkPS)) nchunks = 2;

  float* PO = nullptr;
  float* PS = nullptr;
  if (nchunks > 1) {
    PO = (float*)((char*)d_ws + whbytes);
    PS = (float*)((char*)d_ws + whbytes + (size_t)nchunks * chunkPO);
  }

  gat_proj<<<(8 * S) / 64, 256, 0, stream>>>(feat, W, Wh, WhT);
  gat_attn<<<1024 * nchunks, 256, 0, stream>>>(adj, Wh, WhT, out, PO, PS, 32 / nchunks);
  if (nchunks > 1) gat_reduce<<<2048, 256, 0, stream>>>(PO, PS, out, nchunks);
}